// Round 20
// baseline (499.088 us; speedup 1.0000x reference)
//
#include <hip/hip_runtime.h>
#include <math.h>

// Problem dims (fixed)
#define B_   128
#define L_   256
#define H_   128
#define H2_  256
#define VS_  256

__device__ __forceinline__ float fma4(float4 a, float4 b, float acc) {
    acc = fmaf(a.x, b.x, acc);
    acc = fmaf(a.y, b.y, acc);
    acc = fmaf(a.z, b.z, acc);
    acc = fmaf(a.w, b.w, acc);
    return acc;
}

template <int CTRL>
__device__ __forceinline__ float dpp_add(float x) {
    int y = __builtin_amdgcn_update_dpp(0, __float_as_int(x), CTRL, 0xf, 0xf, true);
    return x + __int_as_float(y);
}
// Full 64-lane sum; total lands in lane 63.
__device__ __forceinline__ float wave_sum(float x) {
    x = dpp_add<0x111>(x);  // row_shr:1
    x = dpp_add<0x112>(x);  // row_shr:2
    x = dpp_add<0x114>(x);  // row_shr:4
    x = dpp_add<0x118>(x);  // row_shr:8
    x = dpp_add<0x142>(x);  // row_bcast:15
    x = dpp_add<0x143>(x);  // row_bcast:31
    return x;
}
// Sum over the 4 lanes of each quad (butterfly -> valid in all 4 lanes).
__device__ __forceinline__ float quad_sum(float x) {
    x = dpp_add<0xB1>(x);   // quad_perm [1,0,3,2]
    x = dpp_add<0x4E>(x);   // quad_perm [2,3,0,1]
    return x;
}

// ---------------------------------------------------------------------------
// Kernel 1: per-VOCAB fused FFN (R11/R18, measured): F[v] = Wk(LN(e+FFN(e))).
// ---------------------------------------------------------------------------
__global__ __launch_bounds__(256) void k_vffn(
    const float* __restrict__ embed,
    const float* __restrict__ W1, const float* __restrict__ b1,
    const float* __restrict__ W2, const float* __restrict__ b2,
    const float* __restrict__ gamma, const float* __restrict__ beta,
    const float* __restrict__ Wk, float* __restrict__ Fout)
{
    __shared__ float sh_h[4][128];
    __shared__ float sh_y[4][256];

    const int tid  = threadIdx.x;
    const int lane = tid & 63;
    const int r    = tid >> 6;
    const int v    = blockIdx.x * 4 + r;

    const float4* embed4 = (const float4*)embed;
    const float4* W1_4   = (const float4*)W1;
    const float4* W2_4   = (const float4*)W2;
    const float4* Wk_4   = (const float4*)Wk;

    if (lane < 32)
        *(float4*)&sh_h[r][lane * 4] = embed4[v * 32 + lane];
    __syncthreads();

    #pragma unroll
    for (int jj = 0; jj < 4; ++jj) {
        int j = jj * 64 + lane;
        const float4* wrow = W1_4 + j * 32;
        float acc = 0.f;
        #pragma unroll
        for (int c4 = 0; c4 < 32; ++c4)
            acc = fma4(*(const float4*)&sh_h[r][c4 * 4], wrow[c4], acc);
        sh_y[r][j] = fmaxf(acc + b1[j], 0.f);
    }
    __syncthreads();

    float xv[4];
    #pragma unroll
    for (int cc = 0; cc < 4; ++cc) {
        int c  = cc * 32 + (lane & 31);
        int hf = lane >> 5;
        const float4* wrow = W2_4 + c * 64 + hf * 32;
        float acc = 0.f;
        #pragma unroll
        for (int j4 = 0; j4 < 32; ++j4)
            acc = fma4(*(const float4*)&sh_y[r][(hf * 32 + j4) * 4], wrow[j4], acc);
        acc += __shfl_xor(acc, 32);
        xv[cc] = acc;
    }
    if (lane < 32) {
        #pragma unroll
        for (int cc = 0; cc < 4; ++cc) {
            int c = cc * 32 + lane;
            sh_h[r][c] = sh_h[r][c] + xv[cc] + b2[c];
        }
    }
    __syncthreads();

    {
        float2 x2 = *(const float2*)&sh_h[r][lane * 2];
        float s  = x2.x + x2.y;
        float s2 = x2.x * x2.x + x2.y * x2.y;
        s  += __shfl_xor(s, 1);  s  += __shfl_xor(s, 2);  s  += __shfl_xor(s, 4);
        s  += __shfl_xor(s, 8);  s  += __shfl_xor(s, 16); s  += __shfl_xor(s, 32);
        s2 += __shfl_xor(s2, 1); s2 += __shfl_xor(s2, 2); s2 += __shfl_xor(s2, 4);
        s2 += __shfl_xor(s2, 8); s2 += __shfl_xor(s2, 16); s2 += __shfl_xor(s2, 32);
        float mu   = s * (1.f / 128.f);
        float var  = s2 * (1.f / 128.f) - mu * mu;
        float rstd = 1.f / sqrtf(var + 1e-5f);
        float2 g2  = *(const float2*)&gamma[lane * 2];
        float2 be2 = *(const float2*)&beta[lane * 2];
        float2 o;
        o.x = (x2.x - mu) * rstd * g2.x + be2.x;
        o.y = (x2.y - mu) * rstd * g2.y + be2.y;
        *(float2*)&sh_h[r][lane * 2] = o;
    }
    __syncthreads();

    #pragma unroll
    for (int kk = 0; kk < 2; ++kk) {
        int k = kk * 64 + lane;
        const float4* wrow = Wk_4 + k * 32;
        float acc = 0.f;
        #pragma unroll
        for (int c4 = 0; c4 < 32; ++c4)
            acc = fma4(*(const float4*)&sh_h[r][c4 * 4], wrow[c4], acc);
        Fout[v * 128 + k] = acc;
    }
}

// ---------------------------------------------------------------------------
// Kernel 2: gated delta-rule scan — R18 layout/algebra/schedule, but ALL
//   k-operand traffic moved OFF the LDS pipe:
//   - k-chunk refills: 8x global_load_dwordx4 from L2-resident F (16 lanes
//     share each address -> HW dedup); issued right after the update (~0.6
//     region lead over next matvec use). No LDS k-store at all.
//   - kself: 3-deep VMEM scalar ring from F.
//   - LDS now only: tables (rna/thr/d01), red partials, epilogue buffers.
//     Barrier drain = red write only (lgkmcnt(0) ~ free); VMEM loads need
//     NO drain at barriers (private register targets).
//   Gate-decoupled matvec (pre = M_{t-1}k_{t+1} + a*d01[t], exact) and fused
//   out-projection epilogue identical to R18.
// ---------------------------------------------------------------------------
__global__ __launch_bounds__(512) void k_scan(
    const int* __restrict__ seq, const float* __restrict__ Fbuf,
    const float* __restrict__ Wr, const float* __restrict__ br,
    const float* __restrict__ Wo, const float* __restrict__ bo,
    float* __restrict__ out)
{
    __shared__ float rna[256];
    __shared__ float thr[256];
    __shared__ float d01[256];
    __shared__ float red_f[16];
    __shared__ float rd_[128];
    __shared__ float r2_[128];
    __shared__ int   seqb_[256];

    const int tid  = threadIdx.x;
    const int lane = tid & 63;
    const int w    = tid >> 6;        // wave id 0..7
    const int cq   = lane & 3;        // col chunk 0..3 (32 cols each)
    const int row  = w * 16 + (lane >> 2);   // 0..127
    const int b    = blockIdx.x;
    const float4* F4 = (const float4*)Fbuf;

    // ---- prologue 0: seq -> LDS ----
    if (tid < 256) seqb_[tid] = seq[b * 256 + tid];
    __syncthreads();

    // ---- prologue 1: per-row norms + neighbor dots (reads F from L2) ----
    {
        int rr = tid >> 4, cc = tid & 15;
        for (int it = 0; it < 8; ++it) {
            int t  = it * 32 + rr;
            int tn = (t < 255) ? t + 1 : 255;
            const float4* A  = F4 + (size_t)seqb_[t]  * 32;
            const float4* Bp = F4 + (size_t)seqb_[tn] * 32;
            float4 a0 = A[cc],  a1 = A[16 + cc];
            float4 b0 = Bp[cc], b1 = Bp[16 + cc];
            float n2p = fma4(a1, a1, fma4(a0, a0, 0.f));
            float cp  = fma4(a1, b1, fma4(a0, b0, 0.f));
            n2p += __shfl_xor(n2p, 1); n2p += __shfl_xor(n2p, 2);
            n2p += __shfl_xor(n2p, 4); n2p += __shfl_xor(n2p, 8);
            cp  += __shfl_xor(cp, 1);  cp  += __shfl_xor(cp, 2);
            cp  += __shfl_xor(cp, 4);  cp  += __shfl_xor(cp, 8);
            if (cc == 0) {
                rna[t] = 1.f / fmaxf(sqrtf(n2p), 1e-12f);
                thr[t] = 0.16f * n2p;
                d01[t] = cp;
            }
        }
    }

    // ---- init: M slice, k chunk buffers (global), kself ring, err_0 ----
    float4 m[8];
    #pragma unroll
    for (int u = 0; u < 8; ++u) m[u] = make_float4(0.f, 0.f, 0.f, 0.f);

    float4 kbE[8], kbO[8];
    {
        const float4* p0 = F4 + (size_t)seqb_[0] * 32 + cq * 8;
        const float4* p1 = F4 + (size_t)seqb_[1] * 32 + cq * 8;
        #pragma unroll
        for (int u = 0; u < 8; ++u) { kbE[u] = p0[u]; kbO[u] = p1[u]; }
    }
    float errR = Fbuf[(size_t)seqb_[0] * 128 + row];   // err_0 = k_0[row]
    float ksA  = Fbuf[(size_t)seqb_[1] * 128 + row];   // kself_1 (used t=0)
    float ksB  = Fbuf[(size_t)seqb_[2] * 128 + row];   // kself_2 (used t=1)
    float ksC  = Fbuf[(size_t)seqb_[3] * 128 + row];   // kself_3 (used t=2)
    {
        float e2p = (cq == 0) ? errR * errR : 0.f;
        e2p = wave_sum(e2p);
        if (lane == 63) red_f[w] = e2p;   // parity-0 slots for region 0
    }
    __syncthreads();   // tables + red visible

#define REGION(T, KU, KM, KS)                                                   \
  {                                                                             \
    const int t_ = (T);                                                         \
    float rnaT = rna[t_], rnaN = rna[t_ + 1];                                   \
    float thrT = thr[t_], d01T = d01[t_];                                       \
    float4 ra = ((const float4*)red_f)[(t_ & 1) * 2];                           \
    float4 rb = ((const float4*)red_f)[(t_ & 1) * 2 + 1];                       \
    /* gate-independent matvec with M_{t-1}, overlaps the red read */           \
    float pA = 0.f, pB = 0.f;                                                   \
    pA = fma4(m[0], KM[0], pA); pB = fma4(m[1], KM[1], pB);                     \
    pA = fma4(m[2], KM[2], pA); pB = fma4(m[3], KM[3], pB);                     \
    pA = fma4(m[4], KM[4], pA); pB = fma4(m[5], KM[5], pB);                     \
    pA = fma4(m[6], KM[6], pA); pB = fma4(m[7], KM[7], pB);                     \
    float preM = quad_sum(pA + pB);                                             \
    float E2 = ((ra.x + ra.y) + (ra.z + ra.w)) +                                \
               ((rb.x + rb.y) + (rb.z + rb.w));                                 \
    float a_ = (E2 >= thrT) ? rnaT * errR : 0.f;                                \
    float pre = fmaf(a_, d01T, preM);    /* = M_t · k_{t+1}, exact */           \
    float errN = fmaf(-rnaN, pre, KS);                                          \
    /* update m -> M_t (consumes KU) */                                         \
    _Pragma("unroll")                                                           \
    for (int u = 0; u < 8; ++u) {                                               \
      m[u].x = fmaf(a_, KU[u].x, m[u].x);                                       \
      m[u].y = fmaf(a_, KU[u].y, m[u].y);                                       \
      m[u].z = fmaf(a_, KU[u].z, m[u].z);                                       \
      m[u].w = fmaf(a_, KU[u].w, m[u].w);                                       \
    }                                                                           \
    /* VMEM refills (L2-hot F; no barrier drain needed for VMEM) */             \
    {                                                                           \
      const float4* ks = F4 + (size_t)seqb_[t_ + 2] * 32 + cq * 8;              \
      _Pragma("unroll")                                                         \
      for (int u = 0; u < 8; ++u) KU[u] = ks[u];                                \
    }                                                                           \
    KS = Fbuf[(size_t)seqb_[(t_ + 4 > 255) ? 255 : t_ + 4] * 128 + row];        \
    /* e2 reduce (errN quad-uniform -> 4-stage) + red write */                  \
    float e2p = errN * errN;                                                    \
    e2p = dpp_add<0x114>(e2p);   /* row_shr:4  */                               \
    e2p = dpp_add<0x118>(e2p);   /* row_shr:8  */                               \
    e2p = dpp_add<0x142>(e2p);   /* row_bcast:15 */                             \
    e2p = dpp_add<0x143>(e2p);   /* row_bcast:31 -> lane63 total */             \
    if (lane == 63) red_f[((t_ + 1) & 1) * 8 + w] = e2p;                        \
    __builtin_amdgcn_sched_barrier(0);                                          \
    asm volatile("s_waitcnt lgkmcnt(0)" ::: "memory");                          \
    __builtin_amdgcn_sched_barrier(0);                                          \
    __builtin_amdgcn_s_barrier();                                               \
    __builtin_amdgcn_sched_barrier(0);                                          \
    errR = errN;                                                                \
  }

    // Regions 0..253 (kb period 2, kself period 3 -> unroll 6).
    for (int tt = 0; tt < 252; tt += 6) {
        REGION(tt + 0, kbE, kbO, ksA);
        REGION(tt + 1, kbO, kbE, ksB);
        REGION(tt + 2, kbE, kbO, ksC);
        REGION(tt + 3, kbO, kbE, ksA);
        REGION(tt + 4, kbE, kbO, ksB);
        REGION(tt + 5, kbO, kbE, ksC);
    }
    REGION(252, kbE, kbO, ksA);
    REGION(253, kbO, kbE, ksB);
#undef REGION

    // ---- epilogue: step 254 fused into readout -> LDS rd_ ----
    {
        float4 ra = ((const float4*)red_f)[0];   // parity (254&1)=0 slots
        float4 rb = ((const float4*)red_f)[1];
        float E2 = ((ra.x + ra.y) + (ra.z + ra.w)) +
                   ((rb.x + rb.y) + (rb.z + rb.w));
        float a_ = (E2 >= thr[254]) ? rna[254] * errR : 0.f;
        float pA = 0.f, pB = 0.f;
        pA = fma4(m[0], kbO[0], pA); pB = fma4(m[1], kbO[1], pB);
        pA = fma4(m[2], kbO[2], pA); pB = fma4(m[3], kbO[3], pB);
        pA = fma4(m[4], kbO[4], pA); pB = fma4(m[5], kbO[5], pB);
        pA = fma4(m[6], kbO[6], pA); pB = fma4(m[7], kbO[7], pB);
        float preM = quad_sum(pA + pB);
        float pre  = fmaf(a_, d01[254], preM);   // M_254 · k_255 = readout
        if (cq == 0) rd_[row] = pre;
    }
    __syncthreads();

    // ---- fused out-projection: out = (rd @ Wr^T + br) @ Wo^T + bo ----
    {
        int i = tid >> 2, q = tid & 3;           // 4 threads per hidden elem
        const float4* Wr4 = (const float4*)Wr;
        const float4* rdv = (const float4*)rd_;
        float s = 0.f;
        #pragma unroll
        for (int u = 0; u < 8; ++u) s = fma4(rdv[q * 8 + u], Wr4[i * 32 + q * 8 + u], s);
        s += __shfl_xor(s, 1);
        s += __shfl_xor(s, 2);
        if (q == 0) r2_[i] = s + br[i];
    }
    __syncthreads();
    {
        int v = tid >> 1, h = tid & 1;           // 2 threads per output elem
        const float4* Wo4 = (const float4*)Wo;
        const float4* r2v = (const float4*)r2_;
        float s = 0.f;
        #pragma unroll
        for (int u = 0; u < 16; ++u) s = fma4(r2v[h * 16 + u], Wo4[v * 32 + h * 16 + u], s);
        s += __shfl_xor(s, 1);
        if (h == 0) out[b * 256 + v] = s + bo[v];
    }
}

// ---------------------------------------------------------------------------
extern "C" void kernel_launch(void* const* d_in, const int* in_sizes, int n_in,
                              void* d_out, int out_size, void* d_ws, size_t ws_size,
                              hipStream_t stream) {
    const int*   seq   = (const int*)  d_in[0];
    const float* embed = (const float*)d_in[1];
    const float* W1    = (const float*)d_in[2];
    const float* b1    = (const float*)d_in[3];
    const float* W2    = (const float*)d_in[4];
    const float* b2    = (const float*)d_in[5];
    const float* gamma = (const float*)d_in[6];
    const float* beta  = (const float*)d_in[7];
    const float* Wk    = (const float*)d_in[8];
    const float* Wr    = (const float*)d_in[9];
    const float* br    = (const float*)d_in[10];
    const float* Wo    = (const float*)d_in[11];
    const float* bo    = (const float*)d_in[12];

    float* Fbuf = (float*)d_ws;                      // 256*128 f32 = 128 KiB
    float* out  = (float*)d_out;

    k_vffn<<<VS_ / 4, 256, 0, stream>>>(embed, W1, b1, W2, b2, gamma, beta, Wk, Fbuf);
    k_scan<<<B_, 512, 0, stream>>>(seq, Fbuf, Wr, br, Wo, bo, out);
}